// Round 2
// baseline (877.665 us; speedup 1.0000x reference)
//
#include <hip/hip_runtime.h>
#include <math.h>

#define N_NODES 100000
#define N_EDGES 1600000
#define NBUK 391          // ceil(N/256) buckets of 256 consecutive dst nodes
#define PCHUNK 8192       // edges per partition block
#define NPBLK 196         // ceil(E/PCHUNK)
#define CHN 64            // nodes per work-stealing chunk in plane-gather kernels

typedef unsigned short u16;
typedef unsigned char u8;
typedef __bf16 bf16x8 __attribute__((ext_vector_type(8)));
typedef float f32x4 __attribute__((ext_vector_type(4)));
typedef float f32x2 __attribute__((ext_vector_type(2)));

// ---- workspace layout (bytes), 16B-aligned ----
#define OFF_RP      0u          // int[N+1]
#define OFF_INVDEG  400016u     // float[N]
#define OFF_BHIST   800016u     // int[392]
#define OFF_BBASE   801600u     // int[392]
#define OFF_GCUR    803200u     // int[391]
#define OFF_PCTR    804800u     // int[64] plane work-steal counters (4 per gather launch)
#define OFF_PAIRS   805056u     // uint2[E] = 12.8 MB
#define OFF_COL     13605056u   // int[E]
#define OFF_PACK    20005056u   // u16[131072] packed bf16 weight fragments
#define OFF_INP     20267200u   // u16[N*128] residual (pre-relu inProj), bf16
#define OFF_H       45867200u   // u16[N*128] h (in-place across layers), bf16, row-major
#define OFF_H8A     71467200u   // u8[4][N][32] fp8 copy of h, PLANE-major, buffer A
#define OFF_H8B     84267200u   // u8[4][N][32] fp8 copy, PLANE-major, buffer B
#define OFF_GL      97067200u   // u16[4][N][16] projected neighbor logits, PLANE-major bf16
#define OFF_GR      109867200u  // u16[N*64] projected root logits, bf16, row-major
#define OFF_MEAN    122667200u  // u16[4][N][32] aggregated mean, PLANE-major bf16
                                // (reused as float[N][64] partial for output stage)
#define WS_NEEDED   148267200u

// packed-weight element offsets (u16 units)
#define PK_WP   0
#define PK_WL   16384
#define PK_WR   65536
#define PK_WLO  114688
#define PK_WRO  122880

__device__ __forceinline__ float bfl(unsigned u) {
  union { unsigned i; float f; } v; v.i = u << 16; return v.f;
}
__device__ __forceinline__ float bfh(unsigned u) {
  union { unsigned i; float f; } v; v.i = u & 0xFFFF0000u; return v.f;
}
__device__ __forceinline__ u16 f2b(float f) {       // RTNE
  union { float f; unsigned i; } v; v.f = f;
  unsigned r = (v.i + 0x7FFFu + ((v.i >> 16) & 1u)) >> 16;
  return (u16)r;
}

// ---------------- pack fp32 weights -> bf16 MFMA B-fragments ----------------
__global__ __launch_bounds__(256) void pack_weights_k(
    const float* __restrict__ Wp, const float* __restrict__ Wl,
    const float* __restrict__ Wr, const float* __restrict__ Wlo,
    const float* __restrict__ Wro, u16* __restrict__ P) {
  int t = blockIdx.x * 256 + threadIdx.x;
  if (t >= 16384) return;
  const float* W; u16* dst; int j; int NT;
  if (t < 2048)        { W = Wp;                    dst = P + PK_WP;                j = t;                 NT = 8; }
  else if (t < 8192)   { int m = (t - 2048) >> 11;  j = (t - 2048) & 2047;
                         W = Wl + (m << 14);        dst = P + PK_WL + (m << 14);    NT = 8; }
  else if (t < 14336)  { int m = (t - 8192) >> 11;  j = (t - 8192) & 2047;
                         W = Wr + (m << 14);        dst = P + PK_WR + (m << 14);    NT = 8; }
  else if (t < 15360)  { j = t - 14336;             W = Wlo;  dst = P + PK_WLO;     NT = 4; }
  else                 { j = t - 15360;             W = Wro;  dst = P + PK_WRO;     NT = 4; }
  int lane = j & 63;
  int nt, kt;
  if (NT == 8) { nt = (j >> 6) & 7; kt = j >> 9; }
  else         { nt = (j >> 6) & 3; kt = j >> 8; }
  int n  = nt * 16 + (lane & 15);
  int k0 = kt * 32 + ((lane >> 4) << 3);
  const float* s = W + n * 128 + k0;
  ushort4 lo = make_ushort4(f2b(s[0]), f2b(s[1]), f2b(s[2]), f2b(s[3]));
  ushort4 hi = make_ushort4(f2b(s[4]), f2b(s[5]), f2b(s[6]), f2b(s[7]));
  *(ushort4*)(dst + j * 8)     = lo;
  *(ushort4*)(dst + j * 8 + 4) = hi;
}

// ---------- bucket histogram ----------
__global__ __launch_bounds__(256) void bhist_k(const int* __restrict__ dst,
                                               int* __restrict__ bhist) {
  __shared__ int lc[NBUK];
  int t = threadIdx.x;
  for (int i = t; i < NBUK; i += 256) lc[i] = 0;
  __syncthreads();
  int base = blockIdx.x * 4096;
#pragma unroll
  for (int r = 0; r < 16; r++) {
    int i = base + r * 256 + t;
    if (i < N_EDGES) atomicAdd(&lc[dst[i] >> 8], 1);
  }
  __syncthreads();
  for (int i = t; i < NBUK; i += 256)
    if (lc[i]) atomicAdd(&bhist[i], lc[i]);
}

// ---------- single-block scan of bucket counts ----------
__global__ __launch_bounds__(512) void bscan_k(const int* __restrict__ bhist,
                                               int* __restrict__ bbase,
                                               int* __restrict__ gcur,
                                               int* __restrict__ rp) {
  __shared__ int s[512];
  int t = threadIdx.x;
  int v = (t < NBUK) ? bhist[t] : 0;
  s[t] = v;
  __syncthreads();
  for (int off = 1; off < 512; off <<= 1) {
    int u = (t >= off) ? s[t - off] : 0;
    __syncthreads();
    s[t] += u;
    __syncthreads();
  }
  if (t < NBUK) { int e = s[t] - v; bbase[t] = e; gcur[t] = e; }
  if (t == NBUK - 1) { bbase[NBUK] = s[t]; rp[N_NODES] = s[t]; }
}

// ---------- partition edges into bucket-contiguous (src,dst) pairs ----------
__global__ __launch_bounds__(256) void part_k(const int* __restrict__ src,
                                              const int* __restrict__ dst,
                                              int* __restrict__ gcur,
                                              uint2* __restrict__ pairs) {
  __shared__ int lcnt[NBUK + 1];
  __shared__ int lofs[512];
  __shared__ int cur[NBUK];
  __shared__ int gslot[NBUK];
  __shared__ uint2 stag[PCHUNK];
  int t = threadIdx.x;
  for (int i = t; i < NBUK + 1; i += 256) lcnt[i] = 0;
  __syncthreads();
  int base = blockIdx.x * PCHUNK;
#pragma unroll
  for (int r = 0; r < PCHUNK / 256; r++) {
    int i = base + r * 256 + t;
    if (i < N_EDGES) atomicAdd(&lcnt[dst[i] >> 8], 1);
  }
  __syncthreads();
  {
    int e1 = t + 256;
    lofs[t]  = (t  <= NBUK) ? lcnt[t]  : 0;
    lofs[e1] = (e1 <= NBUK) ? lcnt[e1] : 0;
    __syncthreads();
    for (int off = 1; off < 512; off <<= 1) {
      int a0 = (t  >= off) ? lofs[t  - off] : 0;
      int a1 = (e1 >= off) ? lofs[e1 - off] : 0;
      __syncthreads();
      lofs[t] += a0; lofs[e1] += a1;
      __syncthreads();
    }
    int o0 = lofs[t]  - ((t  <= NBUK) ? lcnt[t]  : 0);
    int o1 = lofs[e1] - ((e1 <= NBUK) ? lcnt[e1] : 0);
    __syncthreads();
    lofs[t] = o0; lofs[e1] = o1;
    __syncthreads();
  }
  for (int i = t; i < NBUK; i += 256) cur[i] = lofs[i];
  __syncthreads();
#pragma unroll
  for (int r = 0; r < PCHUNK / 256; r++) {
    int i = base + r * 256 + t;
    if (i < N_EDGES) {
      int d = dst[i];
      int slot = atomicAdd(&cur[d >> 8], 1);
      stag[slot] = make_uint2((unsigned)src[i], (unsigned)d);
    }
  }
  __syncthreads();
  for (int i = t; i < NBUK; i += 256)
    if (lcnt[i]) gslot[i] = atomicAdd(&gcur[i], lcnt[i]);
  __syncthreads();
  int total = lofs[NBUK];
  for (int p = t; p < total; p += 256) {
    uint2 pr = stag[p];
    int b = (int)(pr.y >> 8);
    pairs[gslot[b] + (p - lofs[b])] = pr;
  }
}

// ---------- per-bucket CSR finalize ----------
__global__ __launch_bounds__(256) void csr_k(const uint2* __restrict__ pairs,
                                             const int* __restrict__ bbase,
                                             int* __restrict__ rp,
                                             float* __restrict__ invdeg,
                                             int* __restrict__ col) {
  __shared__ int cnt[256];
  __shared__ int scn[256];
  __shared__ int cur[256];
  int b = blockIdx.x, t = threadIdx.x;
  int lo = bbase[b], hi = bbase[b + 1];
  cnt[t] = 0;
  __syncthreads();
  for (int p = lo + t; p < hi; p += 256)
    atomicAdd(&cnt[pairs[p].y & 255], 1);
  __syncthreads();
  int c = cnt[t];
  scn[t] = c;
  __syncthreads();
  for (int off = 1; off < 256; off <<= 1) {
    int v = (t >= off) ? scn[t - off] : 0;
    __syncthreads();
    scn[t] += v;
    __syncthreads();
  }
  int excl = scn[t] - c;
  int node = (b << 8) + t;
  if (node < N_NODES) {
    rp[node] = lo + excl;
    invdeg[node] = 1.0f / (float)(c > 1 ? c : 1);
  }
  cur[t] = lo + excl;
  __syncthreads();
  for (int p = lo + t; p < hi; p += 256) {
    uint2 pr = pairs[p];
    int slot = atomicAdd(&cur[pr.y & 255], 1);
    col[slot] = (int)pr.x;
  }
}

// ------- plane-partitioned mean aggregation from fp8 planes -------
// h8 layout: [4 planes][N][32 bytes]. Each block binds to the plane matching its
// XCD (2 XCDs per plane -> 3.2 MB plane fits 4 MB per-XCD L2), steals 64-node
// chunks via atomic counter; cross-plane stealing guarantees correctness even if
// the XCD mapping assumption fails. mean output is plane-major bf16 [4][N][32].
__global__ __launch_bounds__(256) void aggregate_plane_k(
    const u8* __restrict__ h8, const int* __restrict__ rp,
    const int* __restrict__ col, const float* __restrict__ invdeg,
    int* __restrict__ ctr, u16* __restrict__ mean) {
  __shared__ int sChunk;
  int tid = threadIdx.x;
  int grp = tid >> 3, lane8 = tid & 7;
  int xcc;
  asm volatile("s_getreg_b32 %0, hwreg(HW_REG_XCC_ID)" : "=s"(xcc));
  int myplane = (xcc >> 1) & 3;
  for (int pp = 0; pp < 4; pp++) {
    int pl = (myplane + pp) & 3;
    const u8* hp = h8 + (size_t)pl * (N_NODES * 32) + lane8 * 4;
    u16* mp = mean + (size_t)pl * (N_NODES * 32);
    while (true) {
      __syncthreads();
      if (tid == 0) sChunk = atomicAdd(&ctr[pl], 1);
      __syncthreads();
      int base = sChunk * CHN;
      if (base >= N_NODES) break;
      int lim = base + CHN; if (lim > N_NODES) lim = N_NODES;
      for (int n = base + grp; n < lim; n += 32) {
        int beg = rp[n], end = rp[n + 1];
        float a0 = 0.f, a1 = 0.f, a2 = 0.f, a3 = 0.f;
        int j = beg;
        for (; j + 3 < end; j += 4) {
          int s0 = col[j], s1 = col[j + 1], s2 = col[j + 2], s3 = col[j + 3];
          unsigned v0 = *(const unsigned*)(hp + (size_t)s0 * 32);
          unsigned v1 = *(const unsigned*)(hp + (size_t)s1 * 32);
          unsigned v2 = *(const unsigned*)(hp + (size_t)s2 * 32);
          unsigned v3 = *(const unsigned*)(hp + (size_t)s3 * 32);
          f32x2 p0 = __builtin_amdgcn_cvt_pk_f32_fp8(v0, false);
          f32x2 p1 = __builtin_amdgcn_cvt_pk_f32_fp8(v0, true);
          f32x2 p2 = __builtin_amdgcn_cvt_pk_f32_fp8(v1, false);
          f32x2 p3 = __builtin_amdgcn_cvt_pk_f32_fp8(v1, true);
          f32x2 p4 = __builtin_amdgcn_cvt_pk_f32_fp8(v2, false);
          f32x2 p5 = __builtin_amdgcn_cvt_pk_f32_fp8(v2, true);
          f32x2 p6 = __builtin_amdgcn_cvt_pk_f32_fp8(v3, false);
          f32x2 p7 = __builtin_amdgcn_cvt_pk_f32_fp8(v3, true);
          a0 += (p0[0] + p2[0]) + (p4[0] + p6[0]);
          a1 += (p0[1] + p2[1]) + (p4[1] + p6[1]);
          a2 += (p1[0] + p3[0]) + (p5[0] + p7[0]);
          a3 += (p1[1] + p3[1]) + (p5[1] + p7[1]);
        }
        for (; j < end; j++) {
          unsigned v0 = *(const unsigned*)(hp + (size_t)col[j] * 32);
          f32x2 p0 = __builtin_amdgcn_cvt_pk_f32_fp8(v0, false);
          f32x2 p1 = __builtin_amdgcn_cvt_pk_f32_fp8(v0, true);
          a0 += p0[0]; a1 += p0[1]; a2 += p1[0]; a3 += p1[1];
        }
        float wd = invdeg[n];
        *(ushort4*)(mp + (size_t)n * 32 + lane8 * 4) =
            make_ushort4(f2b(a0 * wd), f2b(a1 * wd), f2b(a2 * wd), f2b(a3 * wd));
      }
    }
  }
}

// ------- plane-partitioned gather of gl (bf16 planes of 16 ch) -> f32 partial [N][64] -------
__global__ __launch_bounds__(256) void out_gather_k(
    const u16* __restrict__ gl, const int* __restrict__ rp,
    const int* __restrict__ col, const float* __restrict__ invdeg,
    int* __restrict__ ctr, float* __restrict__ partial) {
  __shared__ int sChunk;
  int tid = threadIdx.x;
  int grp = tid >> 3, lane8 = tid & 7;
  int xcc;
  asm volatile("s_getreg_b32 %0, hwreg(HW_REG_XCC_ID)" : "=s"(xcc));
  int myplane = (xcc >> 1) & 3;
  for (int pp = 0; pp < 4; pp++) {
    int pl = (myplane + pp) & 3;
    const u16* gp = gl + (size_t)pl * (N_NODES * 16) + lane8 * 2;
    while (true) {
      __syncthreads();
      if (tid == 0) sChunk = atomicAdd(&ctr[pl], 1);
      __syncthreads();
      int base = sChunk * CHN;
      if (base >= N_NODES) break;
      int lim = base + CHN; if (lim > N_NODES) lim = N_NODES;
      for (int n = base + grp; n < lim; n += 32) {
        int beg = rp[n], end = rp[n + 1];
        float a0 = 0.f, a1 = 0.f;
        int j = beg;
        for (; j + 3 < end; j += 4) {
          int s0 = col[j], s1 = col[j + 1], s2 = col[j + 2], s3 = col[j + 3];
          unsigned v0 = *(const unsigned*)(gp + (size_t)s0 * 16);
          unsigned v1 = *(const unsigned*)(gp + (size_t)s1 * 16);
          unsigned v2 = *(const unsigned*)(gp + (size_t)s2 * 16);
          unsigned v3 = *(const unsigned*)(gp + (size_t)s3 * 16);
          a0 += (bfl(v0) + bfl(v1)) + (bfl(v2) + bfl(v3));
          a1 += (bfh(v0) + bfh(v1)) + (bfh(v2) + bfh(v3));
        }
        for (; j < end; j++) {
          unsigned v0 = *(const unsigned*)(gp + (size_t)col[j] * 16);
          a0 += bfl(v0); a1 += bfh(v0);
        }
        float wd = invdeg[n];
        *(float2*)(partial + (size_t)n * 64 + pl * 16 + lane8 * 2) =
            make_float2(a0 * wd, a1 * wd);
      }
    }
  }
}

// ------- output softmax: out = log_softmax(partial + gr + blo), half-wave per node -------
__global__ __launch_bounds__(256) void out_softmax_k(
    const float* __restrict__ partial, const u16* __restrict__ gr,
    const float* __restrict__ blo, float* __restrict__ outp) {
  int node = blockIdx.x * 8 + (threadIdx.x >> 5);
  int lane = threadIdx.x & 31;
  if (node >= N_NODES) return;
  float2 pz = *(const float2*)(partial + (size_t)node * 64 + lane * 2);
  unsigned g = *(const unsigned*)(gr + (size_t)node * 64 + lane * 2);
  float z0 = pz.x + bfl(g) + blo[lane * 2];
  float z1 = pz.y + bfh(g) + blo[lane * 2 + 1];
  float mx = fmaxf(z0, z1);
#pragma unroll
  for (int off = 16; off >= 1; off >>= 1) mx = fmaxf(mx, __shfl_xor(mx, off, 32));
  float s = __expf(z0 - mx) + __expf(z1 - mx);
#pragma unroll
  for (int off = 16; off >= 1; off >>= 1) s += __shfl_xor(s, off, 32);
  float ro = mx + __logf(s);
  float2 o = make_float2(z0 - ro, z1 - ro);
  *(float2*)(outp + (size_t)node * 64 + lane * 2) = o;
}

// ------- inProj: z = x@WpT + bp; inp=bf16(z); h=bf16(relu(z)); h8=fp8(relu(z)) planes -------
__global__ __launch_bounds__(256) void inproj_mfma_k(
    const float* __restrict__ X, const u16* __restrict__ P,
    const float* __restrict__ bias,
    u16* __restrict__ inp, u16* __restrict__ hout, u8* __restrict__ h8out, int M) {
  __shared__ float zb[64 * 132];
  int tid = threadIdx.x;
  int w = tid >> 6, lane = tid & 63;
  int quad = lane >> 4, l15 = lane & 15;
  int m0 = blockIdx.x * 64;
  int rowa = m0 + w * 16 + l15; if (rowa > M - 1) rowa = M - 1;
  f32x4 acc[8] = {};
#pragma unroll
  for (int kt = 0; kt < 4; kt++) {
    const float* xr = X + (long)rowa * 128 + kt * 32 + quad * 8;
    float4 p0 = *(const float4*)xr;
    float4 p1 = *(const float4*)(xr + 4);
    union { ushort4 u4[2]; bf16x8 v; } fa;
    fa.u4[0] = make_ushort4(f2b(p0.x), f2b(p0.y), f2b(p0.z), f2b(p0.w));
    fa.u4[1] = make_ushort4(f2b(p1.x), f2b(p1.y), f2b(p1.z), f2b(p1.w));
    const u16* pb = P + ((kt * 8) * 64 + lane) * 8;
#pragma unroll
    for (int nt = 0; nt < 8; nt++) {
      bf16x8 bf = *(const bf16x8*)(pb + nt * 512);
      acc[nt] = __builtin_amdgcn_mfma_f32_16x16x32_bf16(fa.v, bf, acc[nt], 0, 0, 0);
    }
  }
#pragma unroll
  for (int nt = 0; nt < 8; nt++) {
    int c = nt * 16 + l15;
    float b = bias[c];
#pragma unroll
    for (int r = 0; r < 4; r++)
      zb[(w * 16 + quad * 4 + r) * 132 + c] = acc[nt][r] + b;
  }
  __syncthreads();
  int r = lane >> 2, seg = lane & 3;
  long grow = m0 + w * 16 + r;
  if (grow < M) {
    const float* zrow = &zb[(w * 16 + r) * 132 + seg * 32];
    u16* ip = inp + grow * 128 + seg * 32;
    u16* hp = hout + grow * 128 + seg * 32;
    u8*  qp = h8out + (size_t)seg * (N_NODES * 32) + grow * 32;
#pragma unroll
    for (int b = 0; b < 4; b++) {
      float zv[8];
      *(float4*)&zv[0] = *(const float4*)(zrow + b * 8);
      *(float4*)&zv[4] = *(const float4*)(zrow + b * 8 + 4);
      float rv[8];
#pragma unroll
      for (int jj = 0; jj < 8; jj++) rv[jj] = fmaxf(zv[jj], 0.f);
      *(ushort4*)(ip + b * 8)     = make_ushort4(f2b(zv[0]), f2b(zv[1]), f2b(zv[2]), f2b(zv[3]));
      *(ushort4*)(ip + b * 8 + 4) = make_ushort4(f2b(zv[4]), f2b(zv[5]), f2b(zv[6]), f2b(zv[7]));
      *(ushort4*)(hp + b * 8)     = make_ushort4(f2b(rv[0]), f2b(rv[1]), f2b(rv[2]), f2b(rv[3]));
      *(ushort4*)(hp + b * 8 + 4) = make_ushort4(f2b(rv[4]), f2b(rv[5]), f2b(rv[6]), f2b(rv[7]));
      unsigned q0 = 0, q1 = 0;
      q0 = __builtin_amdgcn_cvt_pk_fp8_f32(rv[0], rv[1], q0, false);
      q0 = __builtin_amdgcn_cvt_pk_fp8_f32(rv[2], rv[3], q0, true);
      q1 = __builtin_amdgcn_cvt_pk_fp8_f32(rv[4], rv[5], q1, false);
      q1 = __builtin_amdgcn_cvt_pk_fp8_f32(rv[6], rv[7], q1, true);
      *(uint2*)(qp + b * 8) = make_uint2(q0, q1);
    }
  }
}

// ------- SAGE layer: h = bf16(relu(mean@Wl + bl + h@Wr) + 0.2*inp), in-place;
//         mean input is PLANE-major; fp8 copy emitted in PLANE-major (h8out may be null) -------
__global__ __launch_bounds__(256) void sage_mfma8_k(
    const u16* __restrict__ A0, const u16* __restrict__ P0,
    const u16* __restrict__ A1, const u16* __restrict__ P1,
    const float* __restrict__ bias, const u16* __restrict__ inp,
    u16* __restrict__ outp, u8* __restrict__ h8out, int M) {
  __shared__ float zb[64 * 132];
  int tid = threadIdx.x;
  int w = tid >> 6, lane = tid & 63;
  int quad = lane >> 4, l15 = lane & 15;
  int m0 = blockIdx.x * 64;
  int rowa = m0 + w * 16 + l15; if (rowa > M - 1) rowa = M - 1;
  f32x4 acc[8] = {};
#pragma unroll
  for (int kt = 0; kt < 4; kt++) {
    bf16x8 am = *(const bf16x8*)(A0 + (size_t)kt * (N_NODES * 32) + (size_t)rowa * 32 + quad * 8);
    bf16x8 ar = *(const bf16x8*)(A1 + (long)rowa * 128 + kt * 32 + quad * 8);
    const u16* pl = P0 + ((kt * 8) * 64 + lane) * 8;
    const u16* pr = P1 + ((kt * 8) * 64 + lane) * 8;
#pragma unroll
    for (int nt = 0; nt < 8; nt++) {
      bf16x8 b0 = *(const bf16x8*)(pl + nt * 512);
      bf16x8 b1 = *(const bf16x8*)(pr + nt * 512);
      acc[nt] = __builtin_amdgcn_mfma_f32_16x16x32_bf16(am, b0, acc[nt], 0, 0, 0);
      acc[nt] = __builtin_amdgcn_mfma_f32_16x16x32_bf16(ar, b1, acc[nt], 0, 0, 0);
    }
  }
#pragma unroll
  for (int nt = 0; nt < 8; nt++) {
    int c = nt * 16 + l15;
    float b = bias[c];
#pragma unroll
    for (int r = 0; r < 4; r++)
      zb[(w * 16 + quad * 4 + r) * 132 + c] = fmaxf(acc[nt][r] + b, 0.f);
  }
  __syncthreads();
  int r = lane >> 2, seg = lane & 3;
  long grow = m0 + w * 16 + r;
  if (grow < M) {
    const float* zrow = &zb[(w * 16 + r) * 132 + seg * 32];
    const u16* ip = inp + grow * 128 + seg * 32;
    u16* op = outp + grow * 128 + seg * 32;
#pragma unroll
    for (int b = 0; b < 4; b++) {
      float zv[8];
      *(float4*)&zv[0] = *(const float4*)(zrow + b * 8);
      *(float4*)&zv[4] = *(const float4*)(zrow + b * 8 + 4);
      uint2 iv0 = *(const uint2*)(ip + b * 8);
      uint2 iv1 = *(const uint2*)(ip + b * 8 + 4);
      float fv[8];
      fv[0] = zv[0] + 0.2f * bfl(iv0.x); fv[1] = zv[1] + 0.2f * bfh(iv0.x);
      fv[2] = zv[2] + 0.2f * bfl(iv0.y); fv[3] = zv[3] + 0.2f * bfh(iv0.y);
      fv[4] = zv[4] + 0.2f * bfl(iv1.x); fv[5] = zv[5] + 0.2f * bfh(iv1.x);
      fv[6] = zv[6] + 0.2f * bfl(iv1.y); fv[7] = zv[7] + 0.2f * bfh(iv1.y);
      *(ushort4*)(op + b * 8)     = make_ushort4(f2b(fv[0]), f2b(fv[1]), f2b(fv[2]), f2b(fv[3]));
      *(ushort4*)(op + b * 8 + 4) = make_ushort4(f2b(fv[4]), f2b(fv[5]), f2b(fv[6]), f2b(fv[7]));
      if (h8out) {
        unsigned q0 = 0, q1 = 0;
        q0 = __builtin_amdgcn_cvt_pk_fp8_f32(fv[0], fv[1], q0, false);
        q0 = __builtin_amdgcn_cvt_pk_fp8_f32(fv[2], fv[3], q0, true);
        q1 = __builtin_amdgcn_cvt_pk_fp8_f32(fv[4], fv[5], q1, false);
        q1 = __builtin_amdgcn_cvt_pk_fp8_f32(fv[6], fv[7], q1, true);
        *(uint2*)(h8out + (size_t)seg * (N_NODES * 32) + grow * 32 + b * 8) = make_uint2(q0, q1);
      }
    }
  }
}

// ------- output projection: gl = h@WloT (PLANE-major), gr = h@WroT (row-major) -------
__global__ __launch_bounds__(256) void out_proj_k(
    const u16* __restrict__ A, const u16* __restrict__ PLO,
    const u16* __restrict__ PRO, u16* __restrict__ gl, u16* __restrict__ gr, int M) {
  __shared__ float zb[64 * 132];
  int tid = threadIdx.x;
  int w = tid >> 6, lane = tid & 63;
  int quad = lane >> 4, l15 = lane & 15;
  int m0 = blockIdx.x * 64;
  int rowa = m0 + w * 16 + l15; if (rowa > M - 1) rowa = M - 1;
  f32x4 acc[8] = {};
#pragma unroll
  for (int kt = 0; kt < 4; kt++) {
    bf16x8 af = *(const bf16x8*)(A + (long)rowa * 128 + kt * 32 + quad * 8);
#pragma unroll
    for (int nt = 0; nt < 4; nt++) {
      bf16x8 b0 = *(const bf16x8*)(PLO + ((kt * 4 + nt) * 64 + lane) * 8);
      bf16x8 b1 = *(const bf16x8*)(PRO + ((kt * 4 + nt) * 64 + lane) * 8);
      acc[nt]     = __builtin_amdgcn_mfma_f32_16x16x32_bf16(af, b0, acc[nt], 0, 0, 0);
      acc[4 + nt] = __builtin_amdgcn_mfma_f32_16x16x32_bf16(af, b1, acc[4 + nt], 0, 0, 0);
    }
  }
  // zb cols 0-63 = gl, 64-127 = gr
#pragma unroll
  for (int nt = 0; nt < 4; nt++) {
    int c = nt * 16 + l15;
#pragma unroll
    for (int r = 0; r < 4; r++) {
      zb[(w * 16 + quad * 4 + r) * 132 + c]      = acc[nt][r];
      zb[(w * 16 + quad * 4 + r) * 132 + 64 + c] = acc[4 + nt][r];
    }
  }
  __syncthreads();
  int r = lane >> 2, seg = lane & 3;
  long grow = m0 + w * 16 + r;
  if (grow < M) {
    const float* zrow = &zb[(w * 16 + r) * 132 + seg * 32];
#pragma unroll
    for (int b = 0; b < 4; b++) {
      float zv[8];
      *(float4*)&zv[0] = *(const float4*)(zrow + b * 8);
      *(float4*)&zv[4] = *(const float4*)(zrow + b * 8 + 4);
      u16* dp;
      if (seg < 2) {
        int plane = seg * 2 + (b >> 1);
        dp = gl + (size_t)plane * (N_NODES * 16) + grow * 16 + (b & 1) * 8;
      } else {
        dp = gr + grow * 64 + (seg - 2) * 32 + b * 8;
      }
      *(ushort4*)(dp)     = make_ushort4(f2b(zv[0]), f2b(zv[1]), f2b(zv[2]), f2b(zv[3]));
      *(ushort4*)(dp + 4) = make_ushort4(f2b(zv[4]), f2b(zv[5]), f2b(zv[6]), f2b(zv[7]));
    }
  }
}

extern "C" void kernel_launch(void* const* d_in, const int* in_sizes, int n_in,
                              void* d_out, int out_size, void* d_ws, size_t ws_size,
                              hipStream_t stream) {
  if (ws_size < (size_t)WS_NEEDED) return;
  const float* x   = (const float*)d_in[0];
  const int*   ei  = (const int*)d_in[1];
  const float* Wp  = (const float*)d_in[2];
  const float* bp  = (const float*)d_in[3];
  const float* Wl  = (const float*)d_in[4];
  const float* bl  = (const float*)d_in[5];
  const float* Wr  = (const float*)d_in[6];
  const float* Wlo = (const float*)d_in[7];
  const float* blo = (const float*)d_in[8];
  const float* Wro = (const float*)d_in[9];
  float* out = (float*)d_out;
  char* ws = (char*)d_ws;
  int*   rp     = (int*)(ws + OFF_RP);
  float* invdeg = (float*)(ws + OFF_INVDEG);
  int*   bhist  = (int*)(ws + OFF_BHIST);
  int*   bbase  = (int*)(ws + OFF_BBASE);
  int*   gcur   = (int*)(ws + OFF_GCUR);
  int*   pctr   = (int*)(ws + OFF_PCTR);
  uint2* pairs  = (uint2*)(ws + OFF_PAIRS);
  int*   col    = (int*)(ws + OFF_COL);
  u16*   pack   = (u16*)(ws + OFF_PACK);
  u16*   inp    = (u16*)(ws + OFF_INP);
  u16*   h      = (u16*)(ws + OFF_H);
  u8*    h8a    = (u8*)(ws + OFF_H8A);
  u8*    h8b    = (u8*)(ws + OFF_H8B);
  u16*   gl     = (u16*)(ws + OFF_GL);
  u16*   gr     = (u16*)(ws + OFF_GR);
  u16*   mean   = (u16*)(ws + OFF_MEAN);
  float* partial = (float*)(ws + OFF_MEAN);   // reused after last sage
  const int* srcv = ei;
  const int* dstv = ei + N_EDGES;

  // zero bhist + bbase + gcur + plane counters in one shot
  hipMemsetAsync(ws + OFF_BHIST, 0, OFF_PAIRS - OFF_BHIST, stream);
  pack_weights_k<<<64, 256, 0, stream>>>(Wp, Wl, Wr, Wlo, Wro, pack);
  bhist_k<<<391, 256, 0, stream>>>(dstv, bhist);
  bscan_k<<<1, 512, 0, stream>>>(bhist, bbase, gcur, rp);
  part_k<<<NPBLK, 256, 0, stream>>>(srcv, dstv, gcur, pairs);
  csr_k<<<NBUK, 256, 0, stream>>>(pairs, bbase, rp, invdeg, col);

  int gblk = (N_NODES + 63) / 64;
  int fblk = (N_NODES + 7) / 8;

  inproj_mfma_k<<<gblk, 256, 0, stream>>>(x, pack + PK_WP, bp, inp, h, h8a, N_NODES);

  aggregate_plane_k<<<1024, 256, 0, stream>>>(h8a, rp, col, invdeg, pctr + 0, mean);
  sage_mfma8_k<<<gblk, 256, 0, stream>>>(mean, pack + PK_WL, h, pack + PK_WR,
                                         bl, inp, h, h8b, N_NODES);
  aggregate_plane_k<<<1024, 256, 0, stream>>>(h8b, rp, col, invdeg, pctr + 4, mean);
  sage_mfma8_k<<<gblk, 256, 0, stream>>>(mean, pack + PK_WL + 16384, h, pack + PK_WR + 16384,
                                         bl + 128, inp, h, h8a, N_NODES);
  aggregate_plane_k<<<1024, 256, 0, stream>>>(h8a, rp, col, invdeg, pctr + 8, mean);
  sage_mfma8_k<<<gblk, 256, 0, stream>>>(mean, pack + PK_WL + 32768, h, pack + PK_WR + 32768,
                                         bl + 256, inp, h, (u8*)nullptr, N_NODES);

  out_proj_k<<<gblk, 256, 0, stream>>>(h, pack + PK_WLO, pack + PK_WRO, gl, gr, N_NODES);
  out_gather_k<<<1024, 256, 0, stream>>>(gl, rp, col, invdeg, pctr + 12, partial);
  out_softmax_k<<<fblk, 256, 0, stream>>>(partial, gr, blo, out);
}

// Round 3
// 546.539 us; speedup vs baseline: 1.6059x; 1.6059x over previous
//
#include <hip/hip_runtime.h>
#include <math.h>

#define N_NODES 100000
#define N_EDGES 1600000
#define NBUK 391          // ceil(N/256) buckets of 256 consecutive dst nodes
#define PCHUNK 8192       // edges per partition block
#define NPBLK 196         // ceil(E/PCHUNK)
#define AGG_BLOCKS 12504  // 8 XCD-slots x 1563 ; covers 4 planes x 3126 idx (guard at 3125)

typedef unsigned short u16;
typedef unsigned char u8;
typedef __bf16 bf16x8 __attribute__((ext_vector_type(8)));
typedef float f32x4 __attribute__((ext_vector_type(4)));
typedef float f32x2 __attribute__((ext_vector_type(2)));

// ---- workspace layout (bytes), 16B-aligned ----
#define OFF_RP      0u          // int[N+1]
#define OFF_INVDEG  400016u     // float[N]
#define OFF_BHIST   800016u     // int[392]
#define OFF_BBASE   801600u     // int[392]
#define OFF_GCUR    803200u     // int[391]
#define OFF_PCTR    804800u     // int[64] (unused this round, kept for layout stability)
#define OFF_PAIRS   805056u     // uint2[E] = 12.8 MB
#define OFF_COL     13605056u   // int[E]
#define OFF_PACK    20005056u   // u16[131072] packed bf16 weight fragments
#define OFF_INP     20267200u   // u16[N*128] residual (pre-relu inProj), bf16
#define OFF_H       45867200u   // u16[N*128] h (in-place across layers), bf16, row-major
#define OFF_H8A     71467200u   // u8[4][N][32] fp8 copy of h, PLANE-major, buffer A
#define OFF_H8B     84267200u   // u8[4][N][32] fp8 copy, PLANE-major, buffer B
#define OFF_GL      97067200u   // u16[4][N][16] projected neighbor logits, PLANE-major bf16
#define OFF_GR      109867200u  // u16[N*64] projected root logits, bf16, row-major
#define OFF_MEAN    122667200u  // u16[4][N][32] aggregated mean, PLANE-major bf16
                                // (reused as float[N][64] partial for output stage)
#define WS_NEEDED   148267200u

// packed-weight element offsets (u16 units)
#define PK_WP   0
#define PK_WL   16384
#define PK_WR   65536
#define PK_WLO  114688
#define PK_WRO  122880

__device__ __forceinline__ float bfl(unsigned u) {
  union { unsigned i; float f; } v; v.i = u << 16; return v.f;
}
__device__ __forceinline__ float bfh(unsigned u) {
  union { unsigned i; float f; } v; v.i = u & 0xFFFF0000u; return v.f;
}
__device__ __forceinline__ u16 f2b(float f) {       // RTNE
  union { float f; unsigned i; } v; v.f = f;
  unsigned r = (v.i + 0x7FFFu + ((v.i >> 16) & 1u)) >> 16;
  return (u16)r;
}

// ---------------- pack fp32 weights -> bf16 MFMA B-fragments ----------------
__global__ __launch_bounds__(256) void pack_weights_k(
    const float* __restrict__ Wp, const float* __restrict__ Wl,
    const float* __restrict__ Wr, const float* __restrict__ Wlo,
    const float* __restrict__ Wro, u16* __restrict__ P) {
  int t = blockIdx.x * 256 + threadIdx.x;
  if (t >= 16384) return;
  const float* W; u16* dst; int j; int NT;
  if (t < 2048)        { W = Wp;                    dst = P + PK_WP;                j = t;                 NT = 8; }
  else if (t < 8192)   { int m = (t - 2048) >> 11;  j = (t - 2048) & 2047;
                         W = Wl + (m << 14);        dst = P + PK_WL + (m << 14);    NT = 8; }
  else if (t < 14336)  { int m = (t - 8192) >> 11;  j = (t - 8192) & 2047;
                         W = Wr + (m << 14);        dst = P + PK_WR + (m << 14);    NT = 8; }
  else if (t < 15360)  { j = t - 14336;             W = Wlo;  dst = P + PK_WLO;     NT = 4; }
  else                 { j = t - 15360;             W = Wro;  dst = P + PK_WRO;     NT = 4; }
  int lane = j & 63;
  int nt, kt;
  if (NT == 8) { nt = (j >> 6) & 7; kt = j >> 9; }
  else         { nt = (j >> 6) & 3; kt = j >> 8; }
  int n  = nt * 16 + (lane & 15);
  int k0 = kt * 32 + ((lane >> 4) << 3);
  const float* s = W + n * 128 + k0;
  ushort4 lo = make_ushort4(f2b(s[0]), f2b(s[1]), f2b(s[2]), f2b(s[3]));
  ushort4 hi = make_ushort4(f2b(s[4]), f2b(s[5]), f2b(s[6]), f2b(s[7]));
  *(ushort4*)(dst + j * 8)     = lo;
  *(ushort4*)(dst + j * 8 + 4) = hi;
}

// ---------- bucket histogram ----------
__global__ __launch_bounds__(256) void bhist_k(const int* __restrict__ dst,
                                               int* __restrict__ bhist) {
  __shared__ int lc[NBUK];
  int t = threadIdx.x;
  for (int i = t; i < NBUK; i += 256) lc[i] = 0;
  __syncthreads();
  int base = blockIdx.x * 4096;
#pragma unroll
  for (int r = 0; r < 16; r++) {
    int i = base + r * 256 + t;
    if (i < N_EDGES) atomicAdd(&lc[dst[i] >> 8], 1);
  }
  __syncthreads();
  for (int i = t; i < NBUK; i += 256)
    if (lc[i]) atomicAdd(&bhist[i], lc[i]);
}

// ---------- single-block scan of bucket counts ----------
__global__ __launch_bounds__(512) void bscan_k(const int* __restrict__ bhist,
                                               int* __restrict__ bbase,
                                               int* __restrict__ gcur,
                                               int* __restrict__ rp) {
  __shared__ int s[512];
  int t = threadIdx.x;
  int v = (t < NBUK) ? bhist[t] : 0;
  s[t] = v;
  __syncthreads();
  for (int off = 1; off < 512; off <<= 1) {
    int u = (t >= off) ? s[t - off] : 0;
    __syncthreads();
    s[t] += u;
    __syncthreads();
  }
  if (t < NBUK) { int e = s[t] - v; bbase[t] = e; gcur[t] = e; }
  if (t == NBUK - 1) { bbase[NBUK] = s[t]; rp[N_NODES] = s[t]; }
}

// ---------- partition edges into bucket-contiguous (src,dst) pairs ----------
__global__ __launch_bounds__(256) void part_k(const int* __restrict__ src,
                                              const int* __restrict__ dst,
                                              int* __restrict__ gcur,
                                              uint2* __restrict__ pairs) {
  __shared__ int lcnt[NBUK + 1];
  __shared__ int lofs[512];
  __shared__ int cur[NBUK];
  __shared__ int gslot[NBUK];
  __shared__ uint2 stag[PCHUNK];
  int t = threadIdx.x;
  for (int i = t; i < NBUK + 1; i += 256) lcnt[i] = 0;
  __syncthreads();
  int base = blockIdx.x * PCHUNK;
#pragma unroll
  for (int r = 0; r < PCHUNK / 256; r++) {
    int i = base + r * 256 + t;
    if (i < N_EDGES) atomicAdd(&lcnt[dst[i] >> 8], 1);
  }
  __syncthreads();
  {
    int e1 = t + 256;
    lofs[t]  = (t  <= NBUK) ? lcnt[t]  : 0;
    lofs[e1] = (e1 <= NBUK) ? lcnt[e1] : 0;
    __syncthreads();
    for (int off = 1; off < 512; off <<= 1) {
      int a0 = (t  >= off) ? lofs[t  - off] : 0;
      int a1 = (e1 >= off) ? lofs[e1 - off] : 0;
      __syncthreads();
      lofs[t] += a0; lofs[e1] += a1;
      __syncthreads();
    }
    int o0 = lofs[t]  - ((t  <= NBUK) ? lcnt[t]  : 0);
    int o1 = lofs[e1] - ((e1 <= NBUK) ? lcnt[e1] : 0);
    __syncthreads();
    lofs[t] = o0; lofs[e1] = o1;
    __syncthreads();
  }
  for (int i = t; i < NBUK; i += 256) cur[i] = lofs[i];
  __syncthreads();
#pragma unroll
  for (int r = 0; r < PCHUNK / 256; r++) {
    int i = base + r * 256 + t;
    if (i < N_EDGES) {
      int d = dst[i];
      int slot = atomicAdd(&cur[d >> 8], 1);
      stag[slot] = make_uint2((unsigned)src[i], (unsigned)d);
    }
  }
  __syncthreads();
  for (int i = t; i < NBUK; i += 256)
    if (lcnt[i]) gslot[i] = atomicAdd(&gcur[i], lcnt[i]);
  __syncthreads();
  int total = lofs[NBUK];
  for (int p = t; p < total; p += 256) {
    uint2 pr = stag[p];
    int b = (int)(pr.y >> 8);
    pairs[gslot[b] + (p - lofs[b])] = pr;
  }
}

// ---------- per-bucket CSR finalize ----------
__global__ __launch_bounds__(256) void csr_k(const uint2* __restrict__ pairs,
                                             const int* __restrict__ bbase,
                                             int* __restrict__ rp,
                                             float* __restrict__ invdeg,
                                             int* __restrict__ col) {
  __shared__ int cnt[256];
  __shared__ int scn[256];
  __shared__ int cur[256];
  int b = blockIdx.x, t = threadIdx.x;
  int lo = bbase[b], hi = bbase[b + 1];
  cnt[t] = 0;
  __syncthreads();
  for (int p = lo + t; p < hi; p += 256)
    atomicAdd(&cnt[pairs[p].y & 255], 1);
  __syncthreads();
  int c = cnt[t];
  scn[t] = c;
  __syncthreads();
  for (int off = 1; off < 256; off <<= 1) {
    int v = (t >= off) ? scn[t - off] : 0;
    __syncthreads();
    scn[t] += v;
    __syncthreads();
  }
  int excl = scn[t] - c;
  int node = (b << 8) + t;
  if (node < N_NODES) {
    rp[node] = lo + excl;
    invdeg[node] = 1.0f / (float)(c > 1 ? c : 1);
  }
  cur[t] = lo + excl;
  __syncthreads();
  for (int p = lo + t; p < hi; p += 256) {
    uint2 pr = pairs[p];
    int slot = atomicAdd(&cur[pr.y & 255], 1);
    col[slot] = (int)pr.x;
  }
}

// ------- plane-partitioned mean aggregation, static XCD-affine mapping -------
// h8 layout: [4 planes][N][32 B]; plane p (3.2 MB) is served by XCDs {2p,2p+1}
// assuming blockIdx -> XCD = blockIdx % 8 (round-robin). Coverage is static and
// mapping-independent: block b handles plane (b%8)>>1, 32-node group (b>>3)*2+(b&1).
// 8 lanes x 4 B per node row; full 12504-block grid restores TLP (no barriers/atomics).
__global__ __launch_bounds__(256) void aggregate_plane_k(
    const u8* __restrict__ h8, const int* __restrict__ rp,
    const int* __restrict__ col, const float* __restrict__ invdeg,
    u16* __restrict__ mean) {
  int b = blockIdx.x;
  int plane = (b & 7) >> 1;
  int idx = ((b >> 3) << 1) + (b & 1);
  if (idx >= 3125) return;
  int tid = threadIdx.x;
  int grp = tid >> 3, lane8 = tid & 7;
  int node = idx * 32 + grp;
  const u8* hp = h8 + (size_t)plane * (N_NODES * 32) + lane8 * 4;
  u16* mp = mean + (size_t)plane * (N_NODES * 32);
  int beg = rp[node], end = rp[node + 1];
  float a0 = 0.f, a1 = 0.f, a2 = 0.f, a3 = 0.f;
  int j = beg;
  for (; j + 3 < end; j += 4) {
    int s0 = col[j], s1 = col[j + 1], s2 = col[j + 2], s3 = col[j + 3];
    unsigned v0 = *(const unsigned*)(hp + (size_t)s0 * 32);
    unsigned v1 = *(const unsigned*)(hp + (size_t)s1 * 32);
    unsigned v2 = *(const unsigned*)(hp + (size_t)s2 * 32);
    unsigned v3 = *(const unsigned*)(hp + (size_t)s3 * 32);
    f32x2 p0 = __builtin_amdgcn_cvt_pk_f32_fp8(v0, false);
    f32x2 p1 = __builtin_amdgcn_cvt_pk_f32_fp8(v0, true);
    f32x2 p2 = __builtin_amdgcn_cvt_pk_f32_fp8(v1, false);
    f32x2 p3 = __builtin_amdgcn_cvt_pk_f32_fp8(v1, true);
    f32x2 p4 = __builtin_amdgcn_cvt_pk_f32_fp8(v2, false);
    f32x2 p5 = __builtin_amdgcn_cvt_pk_f32_fp8(v2, true);
    f32x2 p6 = __builtin_amdgcn_cvt_pk_f32_fp8(v3, false);
    f32x2 p7 = __builtin_amdgcn_cvt_pk_f32_fp8(v3, true);
    a0 += (p0[0] + p2[0]) + (p4[0] + p6[0]);
    a1 += (p0[1] + p2[1]) + (p4[1] + p6[1]);
    a2 += (p1[0] + p3[0]) + (p5[0] + p7[0]);
    a3 += (p1[1] + p3[1]) + (p5[1] + p7[1]);
  }
  for (; j < end; j++) {
    unsigned v0 = *(const unsigned*)(hp + (size_t)col[j] * 32);
    f32x2 p0 = __builtin_amdgcn_cvt_pk_f32_fp8(v0, false);
    f32x2 p1 = __builtin_amdgcn_cvt_pk_f32_fp8(v0, true);
    a0 += p0[0]; a1 += p0[1]; a2 += p1[0]; a3 += p1[1];
  }
  float wd = invdeg[node];
  *(ushort4*)(mp + (size_t)node * 32 + lane8 * 4) =
      make_ushort4(f2b(a0 * wd), f2b(a1 * wd), f2b(a2 * wd), f2b(a3 * wd));
}

// ------- plane-partitioned gather of gl (bf16 planes of 16 ch) -> f32 partial [N][64] -------
__global__ __launch_bounds__(256) void out_gather_k(
    const u16* __restrict__ gl, const int* __restrict__ rp,
    const int* __restrict__ col, const float* __restrict__ invdeg,
    float* __restrict__ partial) {
  int b = blockIdx.x;
  int plane = (b & 7) >> 1;
  int idx = ((b >> 3) << 1) + (b & 1);
  if (idx >= 3125) return;
  int tid = threadIdx.x;
  int grp = tid >> 3, lane8 = tid & 7;
  int node = idx * 32 + grp;
  const u16* gp = gl + (size_t)plane * (N_NODES * 16) + lane8 * 2;
  int beg = rp[node], end = rp[node + 1];
  float a0 = 0.f, a1 = 0.f;
  int j = beg;
  for (; j + 3 < end; j += 4) {
    int s0 = col[j], s1 = col[j + 1], s2 = col[j + 2], s3 = col[j + 3];
    unsigned v0 = *(const unsigned*)(gp + (size_t)s0 * 16);
    unsigned v1 = *(const unsigned*)(gp + (size_t)s1 * 16);
    unsigned v2 = *(const unsigned*)(gp + (size_t)s2 * 16);
    unsigned v3 = *(const unsigned*)(gp + (size_t)s3 * 16);
    a0 += (bfl(v0) + bfl(v1)) + (bfl(v2) + bfl(v3));
    a1 += (bfh(v0) + bfh(v1)) + (bfh(v2) + bfh(v3));
  }
  for (; j < end; j++) {
    unsigned v0 = *(const unsigned*)(gp + (size_t)col[j] * 16);
    a0 += bfl(v0); a1 += bfh(v0);
  }
  float wd = invdeg[node];
  *(float2*)(partial + (size_t)node * 64 + plane * 16 + lane8 * 2) =
      make_float2(a0 * wd, a1 * wd);
}

// ------- output softmax: out = log_softmax(partial + gr + blo), half-wave per node -------
__global__ __launch_bounds__(256) void out_softmax_k(
    const float* __restrict__ partial, const u16* __restrict__ gr,
    const float* __restrict__ blo, float* __restrict__ outp) {
  int node = blockIdx.x * 8 + (threadIdx.x >> 5);
  int lane = threadIdx.x & 31;
  if (node >= N_NODES) return;
  float2 pz = *(const float2*)(partial + (size_t)node * 64 + lane * 2);
  unsigned g = *(const unsigned*)(gr + (size_t)node * 64 + lane * 2);
  float z0 = pz.x + bfl(g) + blo[lane * 2];
  float z1 = pz.y + bfh(g) + blo[lane * 2 + 1];
  float mx = fmaxf(z0, z1);
#pragma unroll
  for (int off = 16; off >= 1; off >>= 1) mx = fmaxf(mx, __shfl_xor(mx, off, 32));
  float s = __expf(z0 - mx) + __expf(z1 - mx);
#pragma unroll
  for (int off = 16; off >= 1; off >>= 1) s += __shfl_xor(s, off, 32);
  float ro = mx + __logf(s);
  float2 o = make_float2(z0 - ro, z1 - ro);
  *(float2*)(outp + (size_t)node * 64 + lane * 2) = o;
}

// ------- inProj: z = x@WpT + bp; inp=bf16(z); h=bf16(relu(z)); h8=fp8(relu(z)) planes -------
__global__ __launch_bounds__(256) void inproj_mfma_k(
    const float* __restrict__ X, const u16* __restrict__ P,
    const float* __restrict__ bias,
    u16* __restrict__ inp, u16* __restrict__ hout, u8* __restrict__ h8out, int M) {
  __shared__ float zb[64 * 132];
  int tid = threadIdx.x;
  int w = tid >> 6, lane = tid & 63;
  int quad = lane >> 4, l15 = lane & 15;
  int m0 = blockIdx.x * 64;
  int rowa = m0 + w * 16 + l15; if (rowa > M - 1) rowa = M - 1;
  f32x4 acc[8] = {};
#pragma unroll
  for (int kt = 0; kt < 4; kt++) {
    const float* xr = X + (long)rowa * 128 + kt * 32 + quad * 8;
    float4 p0 = *(const float4*)xr;
    float4 p1 = *(const float4*)(xr + 4);
    union { ushort4 u4[2]; bf16x8 v; } fa;
    fa.u4[0] = make_ushort4(f2b(p0.x), f2b(p0.y), f2b(p0.z), f2b(p0.w));
    fa.u4[1] = make_ushort4(f2b(p1.x), f2b(p1.y), f2b(p1.z), f2b(p1.w));
    const u16* pb = P + ((kt * 8) * 64 + lane) * 8;
#pragma unroll
    for (int nt = 0; nt < 8; nt++) {
      bf16x8 bf = *(const bf16x8*)(pb + nt * 512);
      acc[nt] = __builtin_amdgcn_mfma_f32_16x16x32_bf16(fa.v, bf, acc[nt], 0, 0, 0);
    }
  }
#pragma unroll
  for (int nt = 0; nt < 8; nt++) {
    int c = nt * 16 + l15;
    float b = bias[c];
#pragma unroll
    for (int r = 0; r < 4; r++)
      zb[(w * 16 + quad * 4 + r) * 132 + c] = acc[nt][r] + b;
  }
  __syncthreads();
  int r = lane >> 2, seg = lane & 3;
  long grow = m0 + w * 16 + r;
  if (grow < M) {
    const float* zrow = &zb[(w * 16 + r) * 132 + seg * 32];
    u16* ip = inp + grow * 128 + seg * 32;
    u16* hp = hout + grow * 128 + seg * 32;
    u8*  qp = h8out + (size_t)seg * (N_NODES * 32) + grow * 32;
#pragma unroll
    for (int b = 0; b < 4; b++) {
      float zv[8];
      *(float4*)&zv[0] = *(const float4*)(zrow + b * 8);
      *(float4*)&zv[4] = *(const float4*)(zrow + b * 8 + 4);
      float rv[8];
#pragma unroll
      for (int jj = 0; jj < 8; jj++) rv[jj] = fmaxf(zv[jj], 0.f);
      *(ushort4*)(ip + b * 8)     = make_ushort4(f2b(zv[0]), f2b(zv[1]), f2b(zv[2]), f2b(zv[3]));
      *(ushort4*)(ip + b * 8 + 4) = make_ushort4(f2b(zv[4]), f2b(zv[5]), f2b(zv[6]), f2b(zv[7]));
      *(ushort4*)(hp + b * 8)     = make_ushort4(f2b(rv[0]), f2b(rv[1]), f2b(rv[2]), f2b(rv[3]));
      *(ushort4*)(hp + b * 8 + 4) = make_ushort4(f2b(rv[4]), f2b(rv[5]), f2b(rv[6]), f2b(rv[7]));
      unsigned q0 = 0, q1 = 0;
      q0 = __builtin_amdgcn_cvt_pk_fp8_f32(rv[0], rv[1], q0, false);
      q0 = __builtin_amdgcn_cvt_pk_fp8_f32(rv[2], rv[3], q0, true);
      q1 = __builtin_amdgcn_cvt_pk_fp8_f32(rv[4], rv[5], q1, false);
      q1 = __builtin_amdgcn_cvt_pk_fp8_f32(rv[6], rv[7], q1, true);
      *(uint2*)(qp + b * 8) = make_uint2(q0, q1);
    }
  }
}

// ------- SAGE layer: h = bf16(relu(mean@Wl + bl + h@Wr) + 0.2*inp), in-place;
//         mean input is PLANE-major; fp8 copy emitted in PLANE-major (h8out may be null) -------
__global__ __launch_bounds__(256) void sage_mfma8_k(
    const u16* __restrict__ A0, const u16* __restrict__ P0,
    const u16* __restrict__ A1, const u16* __restrict__ P1,
    const float* __restrict__ bias, const u16* __restrict__ inp,
    u16* __restrict__ outp, u8* __restrict__ h8out, int M) {
  __shared__ float zb[64 * 132];
  int tid = threadIdx.x;
  int w = tid >> 6, lane = tid & 63;
  int quad = lane >> 4, l15 = lane & 15;
  int m0 = blockIdx.x * 64;
  int rowa = m0 + w * 16 + l15; if (rowa > M - 1) rowa = M - 1;
  f32x4 acc[8] = {};
#pragma unroll
  for (int kt = 0; kt < 4; kt++) {
    bf16x8 am = *(const bf16x8*)(A0 + (size_t)kt * (N_NODES * 32) + (size_t)rowa * 32 + quad * 8);
    bf16x8 ar = *(const bf16x8*)(A1 + (long)rowa * 128 + kt * 32 + quad * 8);
    const u16* pl = P0 + ((kt * 8) * 64 + lane) * 8;
    const u16* pr = P1 + ((kt * 8) * 64 + lane) * 8;
#pragma unroll
    for (int nt = 0; nt < 8; nt++) {
      bf16x8 b0 = *(const bf16x8*)(pl + nt * 512);
      bf16x8 b1 = *(const bf16x8*)(pr + nt * 512);
      acc[nt] = __builtin_amdgcn_mfma_f32_16x16x32_bf16(am, b0, acc[nt], 0, 0, 0);
      acc[nt] = __builtin_amdgcn_mfma_f32_16x16x32_bf16(ar, b1, acc[nt], 0, 0, 0);
    }
  }
#pragma unroll
  for (int nt = 0; nt < 8; nt++) {
    int c = nt * 16 + l15;
    float b = bias[c];
#pragma unroll
    for (int r = 0; r < 4; r++)
      zb[(w * 16 + quad * 4 + r) * 132 + c] = fmaxf(acc[nt][r] + b, 0.f);
  }
  __syncthreads();
  int r = lane >> 2, seg = lane & 3;
  long grow = m0 + w * 16 + r;
  if (grow < M) {
    const float* zrow = &zb[(w * 16 + r) * 132 + seg * 32];
    const u16* ip = inp + grow * 128 + seg * 32;
    u16* op = outp + grow * 128 + seg * 32;
#pragma unroll
    for (int b = 0; b < 4; b++) {
      float zv[8];
      *(float4*)&zv[0] = *(const float4*)(zrow + b * 8);
      *(float4*)&zv[4] = *(const float4*)(zrow + b * 8 + 4);
      uint2 iv0 = *(const uint2*)(ip + b * 8);
      uint2 iv1 = *(const uint2*)(ip + b * 8 + 4);
      float fv[8];
      fv[0] = zv[0] + 0.2f * bfl(iv0.x); fv[1] = zv[1] + 0.2f * bfh(iv0.x);
      fv[2] = zv[2] + 0.2f * bfl(iv0.y); fv[3] = zv[3] + 0.2f * bfh(iv0.y);
      fv[4] = zv[4] + 0.2f * bfl(iv1.x); fv[5] = zv[5] + 0.2f * bfh(iv1.x);
      fv[6] = zv[6] + 0.2f * bfl(iv1.y); fv[7] = zv[7] + 0.2f * bfh(iv1.y);
      *(ushort4*)(op + b * 8)     = make_ushort4(f2b(fv[0]), f2b(fv[1]), f2b(fv[2]), f2b(fv[3]));
      *(ushort4*)(op + b * 8 + 4) = make_ushort4(f2b(fv[4]), f2b(fv[5]), f2b(fv[6]), f2b(fv[7]));
      if (h8out) {
        unsigned q0 = 0, q1 = 0;
        q0 = __builtin_amdgcn_cvt_pk_fp8_f32(fv[0], fv[1], q0, false);
        q0 = __builtin_amdgcn_cvt_pk_fp8_f32(fv[2], fv[3], q0, true);
        q1 = __builtin_amdgcn_cvt_pk_fp8_f32(fv[4], fv[5], q1, false);
        q1 = __builtin_amdgcn_cvt_pk_fp8_f32(fv[6], fv[7], q1, true);
        *(uint2*)(h8out + (size_t)seg * (N_NODES * 32) + grow * 32 + b * 8) = make_uint2(q0, q1);
      }
    }
  }
}

// ------- output projection: gl = h@WloT (PLANE-major), gr = h@WroT (row-major) -------
__global__ __launch_bounds__(256) void out_proj_k(
    const u16* __restrict__ A, const u16* __restrict__ PLO,
    const u16* __restrict__ PRO, u16* __restrict__ gl, u16* __restrict__ gr, int M) {
  __shared__ float zb[64 * 132];
  int tid = threadIdx.x;
  int w = tid >> 6, lane = tid & 63;
  int quad = lane >> 4, l15 = lane & 15;
  int m0 = blockIdx.x * 64;
  int rowa = m0 + w * 16 + l15; if (rowa > M - 1) rowa = M - 1;
  f32x4 acc[8] = {};
#pragma unroll
  for (int kt = 0; kt < 4; kt++) {
    bf16x8 af = *(const bf16x8*)(A + (long)rowa * 128 + kt * 32 + quad * 8);
#pragma unroll
    for (int nt = 0; nt < 4; nt++) {
      bf16x8 b0 = *(const bf16x8*)(PLO + ((kt * 4 + nt) * 64 + lane) * 8);
      bf16x8 b1 = *(const bf16x8*)(PRO + ((kt * 4 + nt) * 64 + lane) * 8);
      acc[nt]     = __builtin_amdgcn_mfma_f32_16x16x32_bf16(af, b0, acc[nt], 0, 0, 0);
      acc[4 + nt] = __builtin_amdgcn_mfma_f32_16x16x32_bf16(af, b1, acc[4 + nt], 0, 0, 0);
    }
  }
  // zb cols 0-63 = gl, 64-127 = gr
#pragma unroll
  for (int nt = 0; nt < 4; nt++) {
    int c = nt * 16 + l15;
#pragma unroll
    for (int r = 0; r < 4; r++) {
      zb[(w * 16 + quad * 4 + r) * 132 + c]      = acc[nt][r];
      zb[(w * 16 + quad * 4 + r) * 132 + 64 + c] = acc[4 + nt][r];
    }
  }
  __syncthreads();
  int r = lane >> 2, seg = lane & 3;
  long grow = m0 + w * 16 + r;
  if (grow < M) {
    const float* zrow = &zb[(w * 16 + r) * 132 + seg * 32];
#pragma unroll
    for (int b = 0; b < 4; b++) {
      float zv[8];
      *(float4*)&zv[0] = *(const float4*)(zrow + b * 8);
      *(float4*)&zv[4] = *(const float4*)(zrow + b * 8 + 4);
      u16* dp;
      if (seg < 2) {
        int plane = seg * 2 + (b >> 1);
        dp = gl + (size_t)plane * (N_NODES * 16) + grow * 16 + (b & 1) * 8;
      } else {
        dp = gr + grow * 64 + (seg - 2) * 32 + b * 8;
      }
      *(ushort4*)(dp)     = make_ushort4(f2b(zv[0]), f2b(zv[1]), f2b(zv[2]), f2b(zv[3]));
      *(ushort4*)(dp + 4) = make_ushort4(f2b(zv[4]), f2b(zv[5]), f2b(zv[6]), f2b(zv[7]));
    }
  }
}

extern "C" void kernel_launch(void* const* d_in, const int* in_sizes, int n_in,
                              void* d_out, int out_size, void* d_ws, size_t ws_size,
                              hipStream_t stream) {
  if (ws_size < (size_t)WS_NEEDED) return;
  const float* x   = (const float*)d_in[0];
  const int*   ei  = (const int*)d_in[1];
  const float* Wp  = (const float*)d_in[2];
  const float* bp  = (const float*)d_in[3];
  const float* Wl  = (const float*)d_in[4];
  const float* bl  = (const float*)d_in[5];
  const float* Wr  = (const float*)d_in[6];
  const float* Wlo = (const float*)d_in[7];
  const float* blo = (const float*)d_in[8];
  const float* Wro = (const float*)d_in[9];
  float* out = (float*)d_out;
  char* ws = (char*)d_ws;
  int*   rp     = (int*)(ws + OFF_RP);
  float* invdeg = (float*)(ws + OFF_INVDEG);
  int*   bhist  = (int*)(ws + OFF_BHIST);
  int*   bbase  = (int*)(ws + OFF_BBASE);
  int*   gcur   = (int*)(ws + OFF_GCUR);
  uint2* pairs  = (uint2*)(ws + OFF_PAIRS);
  int*   col    = (int*)(ws + OFF_COL);
  u16*   pack   = (u16*)(ws + OFF_PACK);
  u16*   inp    = (u16*)(ws + OFF_INP);
  u16*   h      = (u16*)(ws + OFF_H);
  u8*    h8a    = (u8*)(ws + OFF_H8A);
  u8*    h8b    = (u8*)(ws + OFF_H8B);
  u16*   gl     = (u16*)(ws + OFF_GL);
  u16*   gr     = (u16*)(ws + OFF_GR);
  u16*   mean   = (u16*)(ws + OFF_MEAN);
  float* partial = (float*)(ws + OFF_MEAN);   // reused after last sage
  const int* srcv = ei;
  const int* dstv = ei + N_EDGES;

  // zero bhist + bbase + gcur (+pctr slot) in one shot
  hipMemsetAsync(ws + OFF_BHIST, 0, OFF_PAIRS - OFF_BHIST, stream);
  pack_weights_k<<<64, 256, 0, stream>>>(Wp, Wl, Wr, Wlo, Wro, pack);
  bhist_k<<<391, 256, 0, stream>>>(dstv, bhist);
  bscan_k<<<1, 512, 0, stream>>>(bhist, bbase, gcur, rp);
  part_k<<<NPBLK, 256, 0, stream>>>(srcv, dstv, gcur, pairs);
  csr_k<<<NBUK, 256, 0, stream>>>(pairs, bbase, rp, invdeg, col);

  int gblk = (N_NODES + 63) / 64;
  int fblk = (N_NODES + 7) / 8;

  inproj_mfma_k<<<gblk, 256, 0, stream>>>(x, pack + PK_WP, bp, inp, h, h8a, N_NODES);

  aggregate_plane_k<<<AGG_BLOCKS, 256, 0, stream>>>(h8a, rp, col, invdeg, mean);
  sage_mfma8_k<<<gblk, 256, 0, stream>>>(mean, pack + PK_WL, h, pack + PK_WR,
                                         bl, inp, h, h8b, N_NODES);
  aggregate_plane_k<<<AGG_BLOCKS, 256, 0, stream>>>(h8b, rp, col, invdeg, mean);
  sage_mfma8_k<<<gblk, 256, 0, stream>>>(mean, pack + PK_WL + 16384, h, pack + PK_WR + 16384,
                                         bl + 128, inp, h, h8a, N_NODES);
  aggregate_plane_k<<<AGG_BLOCKS, 256, 0, stream>>>(h8a, rp, col, invdeg, mean);
  sage_mfma8_k<<<gblk, 256, 0, stream>>>(mean, pack + PK_WL + 32768, h, pack + PK_WR + 32768,
                                         bl + 256, inp, h, (u8*)nullptr, N_NODES);

  out_proj_k<<<gblk, 256, 0, stream>>>(h, pack + PK_WLO, pack + PK_WRO, gl, gr, N_NODES);
  out_gather_k<<<AGG_BLOCKS, 256, 0, stream>>>(gl, rp, col, invdeg, partial);
  out_softmax_k<<<fblk, 256, 0, stream>>>(partial, gr, blo, out);
}